// Round 4
// baseline (34.163 us; speedup 1.0000x reference)
//
#include <hip/hip_runtime.h>

#define BB 8
#define NN 2048
#define FF 64
#define LOG2E 1.4426950408889634f

typedef float f32x4 __attribute__((ext_vector_type(4)));

// ---------------- Kernel A: fused fold + per-node scores (prescaled) ---------
// ws[i] = sum_o kernel[i,0,o]*aks[o]; wn likewise. S=log2e*enc.ws, T=log2e*enc.wn
__global__ __launch_bounds__(256) void scores_fused(const float* __restrict__ enc,
                                                    const float* __restrict__ kmat,
                                                    const float* __restrict__ aks,
                                                    const float* __restrict__ akn,
                                                    float* __restrict__ S,
                                                    float* __restrict__ T) {
    __shared__ float ws[FF], wn[FF];
    const int tid = threadIdx.x;
    if (tid < FF) {
        float s = 0.f, t = 0.f;
        #pragma unroll
        for (int o = 0; o < FF; ++o) {
            float k = kmat[tid * FF + o];
            s += k * aks[o];
            t += k * akn[o];
        }
        ws[tid] = s;
        wn[tid] = t;
    }
    __syncthreads();

    const int g = blockIdx.x * 256 + tid;
    const f32x4* e4 = (const f32x4*)(enc + (size_t)g * FF);
    const f32x4* w4 = (const f32x4*)ws;
    const f32x4* v4 = (const f32x4*)wn;
    float s = 0.f, t = 0.f;
    #pragma unroll
    for (int j = 0; j < FF / 4; ++j) {
        f32x4 e = e4[j];
        f32x4 w = w4[j];   // LDS broadcast — conflict-free
        f32x4 v = v4[j];
        s += e.x * w.x + e.y * w.y + e.z * w.z + e.w * w.w;
        t += e.x * v.x + e.y * v.y + e.z * v.z + e.w * v.w;
    }
    S[g] = s * LOG2E;
    T[g] = t * LOG2E;
}

// ---------------- Kernel B: one wave per 4 rows (same batch) -----------------
__device__ __forceinline__ float waveMax(float v) {
    #pragma unroll
    for (int o = 32; o > 0; o >>= 1) v = fmaxf(v, __shfl_xor(v, o, 64));
    return v;
}
__device__ __forceinline__ float waveSum(float v) {
    #pragma unroll
    for (int o = 32; o > 0; o >>= 1) v += __shfl_xor(v, o, 64);
    return v;
}
__device__ __forceinline__ float lk(float x) { return fmaxf(x, 0.2f * x); }

#define ROWS_PER_WAVE 4

__global__ __launch_bounds__(256) void softmax_kernel(const float* __restrict__ S,
                                                      const float* __restrict__ T,
                                                      float* __restrict__ out) {
    const int wave = threadIdx.x >> 6;
    const int lane = threadIdx.x & 63;
    const int row0 = (blockIdx.x * 4 + wave) * ROWS_PER_WAVE;  // 4 rows, same batch
    const int b    = row0 >> 11;                               // N = 2048

    const f32x4* t4 = (const f32x4*)(T + (size_t)b * NN);

    // Load the shared T row once into registers (8 KB per wave, coalesced).
    f32x4 t[8];
    float tm = -3.4e38f;
    #pragma unroll
    for (int j = 0; j < 8; ++j) {
        t[j] = t4[lane + 64 * j];
        tm = fmaxf(tm, fmaxf(fmaxf(t[j].x, t[j].y), fmaxf(t[j].z, t[j].w)));
    }
    const float tmax = waveMax(tm);   // once per 4 rows

    #pragma unroll
    for (int r = 0; r < ROWS_PER_WAVE; ++r) {
        const int row = row0 + r;
        const float s = S[row];
        // exact row max: leaky monotone => max_m leaky(s+t_m) = leaky(s+tmax)
        const float M = lk(s + tmax);

        f32x4 e[8];
        float ls = 0.f;
        #pragma unroll
        for (int j = 0; j < 8; ++j) {
            e[j].x = __builtin_exp2f(lk(s + t[j].x) - M);
            e[j].y = __builtin_exp2f(lk(s + t[j].y) - M);
            e[j].z = __builtin_exp2f(lk(s + t[j].z) - M);
            e[j].w = __builtin_exp2f(lk(s + t[j].w) - M);
            ls += (e[j].x + e[j].y) + (e[j].z + e[j].w);
        }
        ls = waveSum(ls);
        const float inv = 1.f / ls;

        f32x4* o4 = (f32x4*)(out + (size_t)row * NN);
        #pragma unroll
        for (int j = 0; j < 8; ++j) {
            f32x4 o;
            o.x = e[j].x * inv; o.y = e[j].y * inv;
            o.z = e[j].z * inv; o.w = e[j].w * inv;
            __builtin_nontemporal_store(o, &o4[lane + 64 * j]);
        }
    }
}

extern "C" void kernel_launch(void* const* d_in, const int* in_sizes, int n_in,
                              void* d_out, int out_size, void* d_ws, size_t ws_size,
                              hipStream_t stream) {
    const float* enc  = (const float*)d_in[0];  // [B,N,F]
    const float* kmat = (const float*)d_in[1];  // [F,1,F]
    const float* aks  = (const float*)d_in[2];  // [F,1,1]
    const float* akn  = (const float*)d_in[3];  // [F,1,1]
    float* out = (float*)d_out;                 // [B,N,N]

    float* W = (float*)d_ws;
    float* S = W;                 // B*N = 16384
    float* T = W + BB * NN;       // 16384

    scores_fused<<<BB * NN / 256, 256, 0, stream>>>(enc, kmat, aks, akn, S, T);
    softmax_kernel<<<BB * NN / (4 * ROWS_PER_WAVE), 256, 0, stream>>>(S, T, out);
}